// Round 1
// baseline (282.388 us; speedup 1.0000x reference)
//
#include <hip/hip_runtime.h>
#include <hip/hip_bf16.h>
#include <float.h>

// Problem constants (B,H,W,D,K) = (16,32,32,256,8192)
#define NROWS 16384
#define DDIM  256
#define KCB   8192
#define ZQ_ELEMS 4194304

// ws layout (4.3 MB; == round-3's proven 4.3 MB)
#define WS_ESQ_OFF   0                      // float[8192]
#define WS_ZSQ_OFF   32768                  // float[16384]
#define WS_CAND_OFF  98304                  // u32[16384*64] = 4 MB
#define WS_PART_OFF  (98304 + 4194304)      // float[4096]
// bf16 copies of z/cb live in d_out scratch (overwritten later by outputs)

#define QWINDOW 410   // rescore window: 0.025 in 1/16384 fixed-point quanta

typedef __attribute__((ext_vector_type(8))) short short8;
typedef __attribute__((ext_vector_type(4))) float floatx4;

__device__ __forceinline__ unsigned short bf16_rn(float f) {
    unsigned u = __float_as_uint(f);
    return (unsigned short)((u + 0x7FFFu + ((u >> 16) & 1u)) >> 16);
}

// async global->LDS DMA, 16 B per lane; LDS dest = wave-uniform base + lane*16
__device__ __forceinline__ void gload_lds16(const void* g, void* l) {
    __builtin_amdgcn_global_load_lds(
        (const __attribute__((address_space(1))) void*)(uintptr_t)g,
        (__attribute__((address_space(3))) void*)(unsigned)(uintptr_t)l, 16, 0, 0);
}

// ---------- prep: bf16 convert + numpy-pairwise sumsq (bit-exact, proven r3) ----
__global__ __launch_bounds__(256) void prep_kernel(
    const float* __restrict__ z, const float* __restrict__ cb,
    unsigned short* __restrict__ z16, unsigned short* __restrict__ cb16,
    float* __restrict__ esq, float* __restrict__ zsq) {
#pragma clang fp contract(off)
    int tid = threadIdx.x;
    int rowb = tid >> 2, sub = tid & 3;
    int b = sub >> 1, jq = sub & 1;
    int row = blockIdx.x * 64 + rowb;
    const float* src; unsigned short* dst; float* o;
    if (row < KCB) { src = cb + (size_t)row * DDIM; dst = cb16 + (size_t)row * DDIM; o = esq + row; }
    else { int r = row - KCB; src = z + (size_t)r * DDIM; dst = z16 + (size_t)r * DDIM; o = zsq + r; }
    float r0 = 0.f, r1 = 0.f, r2 = 0.f, r3 = 0.f;
    for (int t = 0; t < 16; ++t) {
        int off = b * 128 + t * 8 + jq * 4;
        float4 v = *(const float4*)(src + off);
        float q0 = v.x * v.x, q1 = v.y * v.y, q2 = v.z * v.z, q3 = v.w * v.w;
        r0 = r0 + q0; r1 = r1 + q1; r2 = r2 + q2; r3 = r3 + q3;
        ushort4 w;
        w.x = bf16_rn(v.x); w.y = bf16_rn(v.y); w.z = bf16_rn(v.z); w.w = bf16_rn(v.w);
        *(ushort4*)(dst + off) = w;
    }
    float s = (r0 + r1) + (r2 + r3);
    s = s + __shfl_xor(s, 1);   // jq pair
    s = s + __shfl_xor(s, 2);   // block pair
    if (sub == 0) *o = s;
}

// ---------- bf16 MFMA filter: block = 64 z-rows x 256 cols, B streamed from L2 ---
// A(z) 64x256 staged once via global_load_lds (XOR-swizzled). B (cb16, 4 MB,
// L2-resident) is loaded DIRECTLY global->VGPR: the 16x16x32 B-frag is 8
// contiguous bf16 per lane of a cb16 row, i.e. one global_load_dwordx4.
// 2-deep register ring (8 loads in flight) + ZERO main-loop barriers — removes
// the per-step vmcnt(0)+s_barrier drain of the previous LDS-staged version.
// acc = 64 VGPR/wave -> ~155 VGPR total -> 3 waves/SIMD, 3 blocks/CU (LDS 34 KB).
// Epilogue: u32 fixed-point packed keys, top-2 per row per 256-col block
// (64 candidates/row — strictly safer coverage than top-2 per 512).
__global__ __launch_bounds__(256, 3) void gemm_filter_kernel(
    const unsigned short* __restrict__ z16, const unsigned short* __restrict__ cb16,
    const float* __restrict__ esq, unsigned* __restrict__ cand) {
    __shared__ unsigned short As[64 * 256];     // 32 KB
    __shared__ unsigned st[64][4][2];           // 2 KB cross-wave top-2 merge

    const int tid = threadIdx.x;
    const int w = tid >> 6, lane = tid & 63;
    const int c = lane & 15, q = lane >> 4;
    const int m0 = blockIdx.y * 64;
    const int nbase = blockIdx.x * 256;

    // prologue: stage A tile (source-addr XOR swizzle, proven layout)
#pragma unroll
    for (int p = 0; p < 8; ++p) {
        int s = (w * 8 + p) * 64 + lane;
        int row = s >> 5, jp = s & 31;
        int j = (jp & 24) | ((jp & 7) ^ (row & 7));
        gload_lds16(z16 + (size_t)(m0 + row) * 256 + j * 8,
                    (char*)As + (w * 8 + p) * 1024);
    }

    // per-lane B pointers: col = nbase + w*64 + cf*16 + c, k-offset q*8.
    // B-frag(cf,ks) = 8 bf16 at gB[cf] + ks*32 elements — immediate offsets only.
    const unsigned short* gB[4];
#pragma unroll
    for (int cf = 0; cf < 4; ++cf)
        gB[cf] = cb16 + (size_t)(nbase + w * 64 + cf * 16 + c) * 256 + q * 8;

    // prefetch ks=0,1 into the ring before the A barrier (overlaps A DMA)
    short8 bb[3][4];
#pragma unroll
    for (int cf = 0; cf < 4; ++cf) bb[0][cf] = *(const short8*)(gB[cf]);
#pragma unroll
    for (int cf = 0; cf < 4; ++cf) bb[1][cf] = *(const short8*)(gB[cf] + 32);

    floatx4 acc[4][4];   // [f][cf]
#pragma unroll
    for (int f = 0; f < 4; ++f)
#pragma unroll
        for (int cf = 0; cf < 4; ++cf) acc[f][cf] = (floatx4){0.f, 0.f, 0.f, 0.f};

    // A-frag addressing: row = f*16+c, granule g = ks*4+q, byte =
    // f*8192 + c*512 + (g&24)*16 + ((g&7)^(c&7))*16. Only two per-lane bases
    // (ks parity); f and kt go into the 16-bit ds_read immediate.
    const int xorv = (c & 7) * 16;
    const int aeven = c * 512 + ((q * 16) ^ xorv);
    const int aodd  = c * 512 + (((4 + q) * 16) ^ xorv);

    __syncthreads();   // A tile ready (drains initial B prefetch too — once, cheap)

#pragma unroll
    for (int ks = 0; ks < 8; ++ks) {
        if (ks < 6) {   // keep 2 k-steps (8 loads) in flight
#pragma unroll
            for (int cf = 0; cf < 4; ++cf)
                bb[(ks + 2) % 3][cf] = *(const short8*)(gB[cf] + (ks + 2) * 32);
        }
        short8 af[4];
#pragma unroll
        for (int f = 0; f < 4; ++f)
            af[f] = *(const short8*)((const char*)As + f * 8192 +
                                     (ks & 1 ? aodd : aeven) + (ks >> 1) * 128);
#pragma unroll
        for (int f = 0; f < 4; ++f)
#pragma unroll
            for (int cf = 0; cf < 4; ++cf)
                acc[f][cf] = __builtin_amdgcn_mfma_f32_16x16x32_bf16(
                    af[f], bb[ks % 3][cf], acc[f][cf], 0, 0, 0);
    }

    // ---- epilogue (once per block): fixed-point pack + top-2 ----
    float ekf[4]; unsigned kb[4];
#pragma unroll
    for (int cf = 0; cf < 4; ++cf) {
        int col = nbase + w * 64 + cf * 16 + c;
        ekf[cf] = (esq[col] + 8.0f) * 16384.0f;   // key+8 in quanta
        kb[cf] = (unsigned)col;
    }
    unsigned b1[4][4], b2[4][4];
#pragma unroll
    for (int f = 0; f < 4; ++f)
#pragma unroll
        for (int r = 0; r < 4; ++r) { b1[f][r] = 0xFFFFFFFFu; b2[f][r] = 0xFFFFFFFFu; }
#pragma unroll
    for (int f = 0; f < 4; ++f)
#pragma unroll
        for (int r = 0; r < 4; ++r)
#pragma unroll
            for (int cf = 0; cf < 4; ++cf) {
                float fx = fmaf(-32768.0f, acc[f][cf][r], ekf[cf]);
                unsigned p = ((unsigned)fx << 13) | kb[cf];
                unsigned t = min(p, b2[f][r]);
                b2[f][r] = max(t, b1[f][r]);   // med3(p, b1, b2)
                b1[f][r] = min(b1[f][r], p);
            }
#pragma unroll
    for (int f = 0; f < 4; ++f)
#pragma unroll
        for (int r = 0; r < 4; ++r) {
            unsigned x1 = b1[f][r], x2 = b2[f][r];
#pragma unroll
            for (int sft = 1; sft < 16; sft <<= 1) {
                unsigned o1 = __shfl_xor(x1, sft);
                unsigned o2 = __shfl_xor(x2, sft);
                unsigned mx = max(x1, o1);
                x1 = min(x1, o1);
                x2 = min(min(mx, x2), o2);
            }
            if (c == 0) {
                st[f * 16 + q * 4 + r][w][0] = x1;
                st[f * 16 + q * 4 + r][w][1] = x2;
            }
        }
    __syncthreads();
    if (tid < 64) {
        unsigned a1 = st[tid][0][0], a2 = st[tid][0][1];
#pragma unroll
        for (int ww = 1; ww < 4; ++ww) {
            unsigned p1 = st[tid][ww][0], p2 = st[tid][ww][1];
            unsigned mx = max(a1, p1);
            a1 = min(a1, p1);
            a2 = min(min(mx, a2), p2);
        }
        cand[(size_t)(m0 + tid) * 64 + blockIdx.x * 2 + 0] = a1;
        cand[(size_t)(m0 + tid) * 64 + blockIdx.x * 2 + 1] = a2;
    }
}

// ---------- resolve (numpy-replica fp32 rescore, proven r3/r4) + gather ------
__global__ __launch_bounds__(256) void resolve_gather_kernel(
    const float* __restrict__ z, const float* __restrict__ cb,
    const float* __restrict__ zsq, const float* __restrict__ esq,
    const unsigned* __restrict__ cand, float* __restrict__ out,
    float* __restrict__ partials) {
#pragma clang fp contract(off)
    __shared__ float wls[4];
    int w = threadIdx.x >> 6, l = threadIdx.x & 63;
    int row = blockIdx.x * 4 + w;
    unsigned p = cand[(size_t)row * 64 + l];    // 64 candidates/row, one per lane
    unsigned m = p;
#pragma unroll
    for (int s = 32; s; s >>= 1) m = min(m, __shfl_xor(m, s));
    bool active = ((p >> 13) <= (m >> 13) + QWINDOW);
    float dref = FLT_MAX; int k = 0x7FFFFFFF;
    if (active) {
        k = (int)(p & 8191u);
        const float* zr = z + (size_t)row * DDIM;
        const float* er = cb + (size_t)k * DDIM;
        float cacc = 0.f;
        for (int d = 0; d < DDIM; ++d)
            cacc = fmaf(zr[d], er[d], cacc);   // BLAS-style sequential-K fma chain
        float s1 = zsq[row] + esq[k];          // numpy: z_sq + e_sq (fp32 round)
        float two = 2.0f * cacc;               // exact
        dref = s1 - two;                       // single fp32 round
    }
#pragma unroll
    for (int s = 32; s; s >>= 1) {
        float od = __shfl_xor(dref, s);
        int ok = __shfl_xor(k, s);
        if (od < dref || (od == dref && ok < k)) { dref = od; k = ok; }
    }
    if (l == 0) out[ZQ_ELEMS + row] = (float)k;
    float ls = 0.f;
#pragma unroll
    for (int t = 0; t < 4; ++t) {
        int d = l + t * 64;
        float e = cb[(size_t)k * DDIM + d];
        float zv = z[(size_t)row * DDIM + d];
        out[(size_t)row * DDIM + d] = zv + (e - zv);  // z_q_st == z_q numerically
        float df = zv - e;
        ls = fmaf(df, df, ls);
    }
#pragma unroll
    for (int s = 32; s; s >>= 1) ls += __shfl_xor(ls, s);
    if (l == 0) wls[w] = ls;
    __syncthreads();
    if (threadIdx.x == 0)
        partials[blockIdx.x] = (wls[0] + wls[1]) + (wls[2] + wls[3]);
}

__global__ __launch_bounds__(256) void final_kernel(const float* __restrict__ partials,
                                                    float* __restrict__ out) {
    __shared__ double wd[4];
    int w = threadIdx.x >> 6, l = threadIdx.x & 63;
    double s = 0.0;
#pragma unroll
    for (int j = 0; j < 16; ++j) s += (double)partials[threadIdx.x + j * 256];
#pragma unroll
    for (int sh = 32; sh; sh >>= 1) s += __shfl_xor(s, sh);
    if (l == 0) wd[w] = s;
    __syncthreads();
    if (threadIdx.x == 0)
        out[ZQ_ELEMS + NROWS] =
            (float)(1.25 * ((wd[0] + wd[1]) + (wd[2] + wd[3])) / (double)ZQ_ELEMS);
}

extern "C" void kernel_launch(void* const* d_in, const int* in_sizes, int n_in,
                              void* d_out, int out_size, void* d_ws, size_t ws_size,
                              hipStream_t stream) {
    const float* z = (const float*)d_in[0];
    const float* cb = (const float*)d_in[1];
    float* out = (float*)d_out;
    char* ws = (char*)d_ws;
    float* esq = (float*)(ws + WS_ESQ_OFF);
    float* zsq = (float*)(ws + WS_ZSQ_OFF);
    unsigned* cand = (unsigned*)(ws + WS_CAND_OFF);
    float* partials = (float*)(ws + WS_PART_OFF);
    // bf16 scratch inside d_out (12 MB < 16.8 MB); overwritten by outputs later
    unsigned short* z16 = (unsigned short*)d_out;
    unsigned short* cb16 = z16 + (size_t)NROWS * DDIM;

    prep_kernel<<<dim3((KCB + NROWS) / 64), 256, 0, stream>>>(z, cb, z16, cb16, esq, zsq);
    gemm_filter_kernel<<<dim3(32, NROWS / 64), 256, 0, stream>>>(z16, cb16, esq, cand);
    resolve_gather_kernel<<<dim3(NROWS / 4), 256, 0, stream>>>(z, cb, zsq, esq, cand, out, partials);
    final_kernel<<<1, 256, 0, stream>>>(partials, out);
}